// Round 6
// baseline (3154.670 us; speedup 1.0000x reference)
//
#include <hip/hip_runtime.h>
#include <cstdint>

// FPS: B=8, N=131072, NPOINT=1024.  Exact-index replication of the jax reference.
//
// v6: dual-path exchange with ZERO engagement heuristics (v4/v5's sticky
// disable misfired on startup skew both times and silently ran the old
// protocol). Changes vs the proven v0 skeleton (16 blocks/batch, 1024 thr,
// one barrier/round, monotone tag-packed keys, parity dbuf, no resets):
//   * Posts carry COORDS: slot = 4 tagged u64 {key, t|x, t|y, t|z}. Kills the
//     dependent winner-xyz re-fetch from the critical chain. Every word has
//     the round tag in bits [63:49]; acceptance = all 4 tags match, so torn
//     arrival, out-of-order stores, stale L2 lines and parity reuse are all
//     rejected (old words can only carry OLD tags; poison tag 0x2AAA never
//     matches).
//   * Fan-in: per-wave winner {key,x,y,z} -> LDS cells (ballot+readlane gets
//     the wave winner's coords from its registers); after the single barrier,
//     wave 0 reduces 16 cells in-register and lane 0 posts. Replaces 16
//     serialized LDS atomic-maxes on one address.
//   * Dual post, dual poll: lane 0 posts the block winner BOTH as plain
//     stores -> fastbuf (write-through vL1 -> home-XCD L2; blocks of a batch
//     should share an XCD under round-robin dispatch b = blockIdx&7) AND as
//     agent-scope stores -> agentbuf (MALL; correct on ANY placement).
//     Pollers rotate trips 2-fast(sc0):1-agent forever. Progress never
//     depends on the fast path: every 3rd trip is the proven agent path.
//     If fast is visible the detect period drops ~800cy -> ~350cy; if dead,
//     bounded cost ~+0.3us/round.  This round is the decisive experiment for
//     the XCD-L2 hypothesis.
// Key u64: [t:15][fp32 dist bits:32][(~idx)&0x1FFFF:17] -> unsigned max ==
// (round, dist desc, idx asc) == np.argmax first-max tie-break.

constexpr int kB = 8;
constexpr int kN = 131072;
constexpr int kNpoint = 1024;
constexpr int kBlocksPerBatch = 16;
constexpr int kThreads = 1024;
constexpr int kWaves = kThreads / 64;          // 16
constexpr int kPPT = 8;
constexpr int kPtsPerBlock = kThreads * kPPT;  // 8192

typedef float f32x2 __attribute__((ext_vector_type(2)));
typedef uint32_t u32x4 __attribute__((ext_vector_type(4)));

__device__ __forceinline__ uint64_t u64max(uint64_t a, uint64_t b) {
    return a > b ? a : b;
}

template <int CTRL>
__device__ __forceinline__ uint64_t dpp_u64(uint64_t v) {
    int lo = __builtin_amdgcn_update_dpp(0, (int)(uint32_t)v, CTRL, 0xF, 0xF, false);
    int hi = __builtin_amdgcn_update_dpp(0, (int)(uint32_t)(v >> 32), CTRL, 0xF, 0xF, false);
    return ((uint64_t)(uint32_t)hi << 32) | (uint32_t)lo;
}

// Full-wave max; result valid in lane 63 (row_shr/row_bcast ladder; invalid
// source lanes read 0 = identity for our non-negative packed keys).
__device__ __forceinline__ uint64_t wave_max_to_lane63(uint64_t v) {
    v = u64max(v, dpp_u64<0x111>(v));  // row_shr:1
    v = u64max(v, dpp_u64<0x112>(v));  // row_shr:2
    v = u64max(v, dpp_u64<0x114>(v));  // row_shr:4
    v = u64max(v, dpp_u64<0x118>(v));  // row_shr:8
    v = u64max(v, dpp_u64<0x142>(v));  // row_bcast:15
    v = u64max(v, dpp_u64<0x143>(v));  // row_bcast:31
    return v;
}

// Max over each aligned group of 16 lanes (butterfly xor1,2,4,8).
__device__ __forceinline__ uint64_t group16_max(uint64_t v) {
    v = u64max(v, dpp_u64<0xB1>(v));   // quad_perm xor1
    v = u64max(v, dpp_u64<0x4E>(v));   // quad_perm xor2
    v = u64max(v, dpp_u64<0x141>(v));  // row_half_mirror
    v = u64max(v, dpp_u64<0x140>(v));  // row_mirror
    return v;
}

__device__ __forceinline__ uint64_t ld_u64_agent(const uint64_t* p) {
    return __hip_atomic_load(p, __ATOMIC_RELAXED, __HIP_MEMORY_SCOPE_AGENT);
}
__device__ __forceinline__ void st_u64_agent(uint64_t* p, uint64_t v) {
    __hip_atomic_store(p, v, __ATOMIC_RELAXED, __HIP_MEMORY_SCOPE_AGENT);
}

// Fast slot read: 32 B via two dwordx4, L1-bypass (sc0 -> served by L2),
// waitcnt fused in the same asm so the tag check can't be hoisted (rule #18).
__device__ __forceinline__ void ld_slot_l2(const uint64_t* p, uint64_t& w0,
                                           uint64_t& w1, uint64_t& w2, uint64_t& w3) {
    u32x4 A, Bv;
    asm volatile("global_load_dwordx4 %0, %2, off sc0\n\t"
                 "global_load_dwordx4 %1, %2, off offset:16 sc0\n\t"
                 "s_waitcnt vmcnt(0)"
                 : "=&v"(A), "=&v"(Bv) : "v"(p) : "memory");
    w0 = ((uint64_t)A.y << 32) | A.x;
    w1 = ((uint64_t)A.w << 32) | A.z;
    w2 = ((uint64_t)Bv.y << 32) | Bv.x;
    w3 = ((uint64_t)Bv.w << 32) | Bv.z;
}
// Fast slot write: plain stores (write-through vL1 -> home-XCD L2).
__device__ __forceinline__ void st_slot_plain(uint64_t* p, uint64_t w0, uint64_t w1,
                                              uint64_t w2, uint64_t w3) {
    u32x4 A = {(uint32_t)w0, (uint32_t)(w0 >> 32), (uint32_t)w1, (uint32_t)(w1 >> 32)};
    u32x4 Bv = {(uint32_t)w2, (uint32_t)(w2 >> 32), (uint32_t)w3, (uint32_t)(w3 >> 32)};
    asm volatile("global_store_dwordx4 %0, %1, off\n\t"
                 "global_store_dwordx4 %0, %2, off offset:16"
                 :: "v"(p), "v"(A), "v"(Bv) : "memory");
}

__global__ __launch_bounds__(kThreads, 4) void fps_kernel(
        const float* __restrict__ xyz, float* __restrict__ out,
        uint64_t* __restrict__ ws) {
#pragma clang fp contract(off)
    const int b    = blockIdx.x & 7;    // batch; 16 blocks/batch
    const int blk  = blockIdx.x >> 3;   // block within batch, 0..15
    const int tid  = threadIdx.x;
    const int lane = tid & 63;
    const int wave = tid >> 6;          // 0..15

    uint64_t* const fastbuf  = ws;                               // [2][8][16][4]
    uint64_t* const agentbuf = ws + 2 * kB * kBlocksPerBatch * 4;  // same shape

    const float* __restrict__ base = xyz + (size_t)b * kN * 3;

    // Register-resident state as packed pairs: .x is point j=2q, .y is j=2q+1
    // (ascending index order preserved for the first-max tie-break).
    f32x2 X[4], Y[4], Z[4], MD[4];
#pragma unroll
    for (int q = 0; q < 4; ++q) {
        const int p0 = blk * kPtsPerBlock + (2 * q) * kThreads + tid;
        const int p1 = p0 + kThreads;
        X[q].x = base[3 * p0 + 0]; X[q].y = base[3 * p1 + 0];
        Y[q].x = base[3 * p0 + 1]; Y[q].y = base[3 * p1 + 1];
        Z[q].x = base[3 * p0 + 2]; Z[q].y = base[3 * p1 + 2];
        MD[q].x = __builtin_inff(); MD[q].y = __builtin_inff();
    }

    // Per-wave winner cells (written each round before the barrier, read by
    // wave 0 after it -- no init or parity needed: waves can't start round
    // t+1's writes before wave 0's round-t post, which follows its reads).
    __shared__ uint64_t swkey[kWaves];
    __shared__ uint32_t swx[kWaves], swy[kWaves], swz[kWaves];

    // First sample is always point 0.
    float cx = base[0], cy = base[1], cz = base[2];
    if (blk == 0 && tid == 0) {
        float* o = out + (size_t)b * kNpoint * 3;
        o[0] = cx; o[1] = cy; o[2] = cz;
    }

    for (int t = 1; t < kNpoint; ++t) {
        // --- mindist update + per-thread argmax (exact fp32, no contraction) ---
        const f32x2 vcx = {cx, cx}, vcy = {cy, cy}, vcz = {cz, cz};
        float bm = -1.0f;
        int   bj = 0;
#pragma unroll
        for (int q = 0; q < 4; ++q) {
            const f32x2 dx = X[q] - vcx;
            const f32x2 dy = Y[q] - vcy;
            const f32x2 dz = Z[q] - vcz;
            const f32x2 d  = (dx * dx + dy * dy) + dz * dz;  // (xx+yy)+zz, RN
            f32x2 m;
            m.x = fminf(MD[q].x, d.x);
            m.y = fminf(MD[q].y, d.y);
            MD[q] = m;
            // .x is the smaller index -- evaluate first; strict > keeps first max
            const bool g0 = m.x > bm;  bj = g0 ? (2 * q)     : bj;  bm = g0 ? m.x : bm;
            const bool g1 = m.y > bm;  bj = g1 ? (2 * q + 1) : bj;  bm = g1 ? m.y : bm;
        }
        const uint32_t p = (uint32_t)(blk * kPtsPerBlock + bj * kThreads + tid);
        const uint64_t mykey = ((uint64_t)t << 49) |
                               ((uint64_t)__float_as_uint(bm) << 17) |
                               ((~p) & 0x1FFFFu);

        // --- wave winner + owner's coords from registers (ballot/readlane) ---
        const uint64_t wk  = wave_max_to_lane63(mykey);
        const uint32_t whi = (uint32_t)__builtin_amdgcn_readlane((int)(uint32_t)(wk >> 32), 63);
        const uint32_t wlo = (uint32_t)__builtin_amdgcn_readlane((int)(uint32_t)wk, 63);
        const uint64_t wwin = ((uint64_t)whi << 32) | wlo;
        const int owner = __ffsll((unsigned long long)__ballot(mykey == wwin)) - 1;
        const int sbj   = __builtin_amdgcn_readlane(bj, owner);  // uniform
        float fx, fy, fz;
        switch (sbj) {
            case 0:  fx = X[0].x; fy = Y[0].x; fz = Z[0].x; break;
            case 1:  fx = X[0].y; fy = Y[0].y; fz = Z[0].y; break;
            case 2:  fx = X[1].x; fy = Y[1].x; fz = Z[1].x; break;
            case 3:  fx = X[1].y; fy = Y[1].y; fz = Z[1].y; break;
            case 4:  fx = X[2].x; fy = Y[2].x; fz = Z[2].x; break;
            case 5:  fx = X[2].y; fy = Y[2].y; fz = Z[2].y; break;
            case 6:  fx = X[3].x; fy = Y[3].x; fz = Z[3].x; break;
            default: fx = X[3].y; fy = Y[3].y; fz = Z[3].y; break;
        }
        const uint32_t ox = (uint32_t)__builtin_amdgcn_readlane((int)__float_as_uint(fx), owner);
        const uint32_t oy = (uint32_t)__builtin_amdgcn_readlane((int)__float_as_uint(fy), owner);
        const uint32_t oz = (uint32_t)__builtin_amdgcn_readlane((int)__float_as_uint(fz), owner);
        if (lane == 0) {
            swkey[wave] = wwin; swx[wave] = ox; swy[wave] = oy; swz[wave] = oz;
        }
        __syncthreads();  // the one barrier: all 16 wave winners in LDS

        const size_t sbOff = ((size_t)(t & 1) * kB + b) * (kBlocksPerBatch * 4);
        uint64_t* const fslot = fastbuf + sbOff;
        uint64_t* const aslot = agentbuf + sbOff;
        const uint64_t tag = (uint64_t)t << 49;

        // --- wave 0: reduce the 16 cells, lane 0 posts (fast + agent) ---
        if (wave == 0) {
            const bool live = lane < kWaves;
            const uint64_t k = live ? swkey[lane] : 0;
            const uint32_t xx = live ? swx[lane] : 0;
            const uint32_t yy = live ? swy[lane] : 0;
            const uint32_t zz = live ? swz[lane] : 0;
            const uint64_t g = group16_max(k);
            const int wo = __ffsll((unsigned long long)__ballot((k == g) & (lane < 16))) - 1;
            const uint32_t gx = (uint32_t)__builtin_amdgcn_readlane((int)xx, wo);
            const uint32_t gy = (uint32_t)__builtin_amdgcn_readlane((int)yy, wo);
            const uint32_t gz = (uint32_t)__builtin_amdgcn_readlane((int)zz, wo);
            if (lane == 0) {
                const uint64_t w1 = tag | ((uint64_t)gx << 17);
                const uint64_t w2 = tag | ((uint64_t)gy << 17);
                const uint64_t w3 = tag | ((uint64_t)gz << 17);
                st_slot_plain(&fslot[(size_t)blk * 4], g, w1, w2, w3);  // home L2
                uint64_t* const q = &aslot[(size_t)blk * 4];            // MALL
                st_u64_agent(q + 0, g);  st_u64_agent(q + 1, w1);
                st_u64_agent(q + 2, w2); st_u64_agent(q + 3, w3);
            }
        }

        // --- every wave polls: lanes 0-15, one slot each, 2 fast : 1 agent ---
        uint64_t w0 = 0, w1 = 0, w2 = 0, w3 = 0;
        bool need = lane < kBlocksPerBatch;
        int phase = 0;
        const uint64_t tt = (uint64_t)t;
        while (__any(need)) {
            if (need) {
                uint64_t a0, a1, a2, a3;
                if (phase != 2) {
                    ld_slot_l2(&fslot[(size_t)lane * 4], a0, a1, a2, a3);
                } else {
                    const uint64_t* q = &aslot[(size_t)lane * 4];
                    a0 = ld_u64_agent(q + 0); a1 = ld_u64_agent(q + 1);
                    a2 = ld_u64_agent(q + 2); a3 = ld_u64_agent(q + 3);
                }
                if (((a0 >> 49) == tt) & ((a1 >> 49) == tt) &
                    ((a2 >> 49) == tt) & ((a3 >> 49) == tt)) {
                    w0 = a0; w1 = a1; w2 = a2; w3 = a3; need = false;
                }
            }
            phase = (phase == 2) ? 0 : phase + 1;
        }
        // batch winner + coords, all from the exchange (no xyz re-fetch)
        const uint64_t g = group16_max(w0);
        const int wo = __ffsll((unsigned long long)__ballot(
                               (w0 == g) & (lane < kBlocksPerBatch))) - 1;
        cx = __uint_as_float((uint32_t)__builtin_amdgcn_readlane((int)(uint32_t)(w1 >> 17), wo));
        cy = __uint_as_float((uint32_t)__builtin_amdgcn_readlane((int)(uint32_t)(w2 >> 17), wo));
        cz = __uint_as_float((uint32_t)__builtin_amdgcn_readlane((int)(uint32_t)(w3 >> 17), wo));
        if (blk == 0 && wave == 0 && lane == 0) {
            float* o = out + ((size_t)b * kNpoint + t) * 3;
            o[0] = cx; o[1] = cy; o[2] = cz;
        }
    }
}

extern "C" void kernel_launch(void* const* d_in, const int* in_sizes, int n_in,
                              void* d_out, int out_size, void* d_ws, size_t ws_size,
                              hipStream_t stream) {
    const float* xyz = (const float*)d_in[0];
    float* out = (float*)d_out;
    uint64_t* ws = (uint64_t*)d_ws;  // fastbuf 8 KiB + agentbuf 8 KiB
    fps_kernel<<<dim3(kB * kBlocksPerBatch), dim3(kThreads), 0, stream>>>(xyz, out, ws);
}